// Round 10
// baseline (42.884 us; speedup 1.0000x reference)
//
#include <hip/hip_runtime.h>
#include <math.h>

// Problem constants (fixed by the reference)
#define B_   16
#define F_   32
#define NP_  128   // rows per (b,f) panel
#define D_   512
#define P_   16
#define KC   32            // K-chunk in floats (128 B per row per chunk)
#define NCH  (D_ / KC)     // 16 chunks; each = 2 MFMA k-steps (K=16)
#define BUFW (NP_ * KC)    // 4096 floats per buffer (16 KB)

typedef __attribute__((ext_vector_type(8)))  short  short8;   // 8 bf16 = 4 VGPR
typedef __attribute__((ext_vector_type(16))) float  floatx16; // 32x32 acc

union Frag { short8 v; unsigned int u[4]; };

__device__ inline unsigned int cvt_pk_bf16(float lo, float hi) {
    unsigned int r;
    asm volatile("v_cvt_pk_bf16_f32 %0, %1, %2" : "=v"(r) : "v"(lo), "v"(hi));
    return r;   // low 16 = bf16(lo), high 16 = bf16(hi)
}

// 512 threads = 8 waves = 4 M-tiles(32 rows) x 2 K-parities; 2 blocks/CU.
// R9 (MFMA, bf16-in/fp32-acc) + deep staging ring: 4 LDS buffers (KC=32),
// prefetch depth 2, ONE barrier per chunk, counted vmcnt (never 0 mid-loop).
// Order per iter: STAGE(c+2) -> vmcnt(4) -> s_barrier -> compute(c).
//  - overwrite safety: buf[(c+2)&3] last read at compute(c-2), two barriers ago
//  - cross-wave visibility: each wave waits ITS chunk-c loads, THEN barriers
__global__ __launch_bounds__(512, 4)
void pd_kernel(const float* __restrict__ ts,
               const float* __restrict__ W,
               const float* __restrict__ bias,
               float* __restrict__ out, int T)
{
    __shared__ float smem[4 * BUFW];   // 64 KB ring; reused by epilogue

    const int tid  = threadIdx.x;
    const int lane = tid & 63;
    const int wave = tid >> 6;       // 0..7
    const int mt   = wave & 3;       // M-tile: rows 32*mt .. +31
    const int p    = wave >> 2;      // k-step parity (0/1)

    // XCD-aware block-id encoding (proven: WRITE_SIZE at ideal ~4.1 MB)
    const int d = blockIdx.x;
    const int b = (d & 7) | ((d >> 8) << 3);
    const int f = (d >> 3) & 31;
    const float* __restrict__ tsb = ts + ((size_t)b * F_ + f) * NP_ * D_;

    // Stage chunk cc into ring buffer cc&3. LDS slot (row rr, quad ql) holds
    // global quad ql^(rr&7) — bijective per row; read side uses same XOR.
    auto STAGE = [&](int cc) {
        const int k0 = cc * KC;
        float* dstb = smem + (cc & 3) * BUFW;
#pragma unroll
        for (int it = 0; it < 2; ++it) {
            int slot = it * 512 + tid;       // 0..1023 16B-slots (128 rows x 8 quads)
            int rr = slot >> 3;
            int ql = slot & 7;
            int qg = ql ^ (rr & 7);
            const float* src = tsb + rr * D_ + k0 + (qg << 2);
            __builtin_amdgcn_global_load_lds(
                (const __attribute__((address_space(1))) unsigned int*)src,
                (__attribute__((address_space(3))) unsigned int*)&dstb[slot << 2],
                16, 0, 0);
        }
    };

    // ---- B preload: wave's 16 k-steps s = 2c+p. Lane: e=lane&31, kh=lane>>5.
    const int e_b = lane & 31;
    const int kh  = lane >> 5;
    Frag bf[NCH];
    {
        const float* wb = W + (size_t)e_b * D_ + kh * 8;
#pragma unroll
        for (int c = 0; c < NCH; ++c) {
            const int k = c * 32 + p * 16;           // + kh*8 folded into wb
            const float4 lo = *(const float4*)(wb + k);
            const float4 hi = *(const float4*)(wb + k + 4);
            bf[c].u[0] = cvt_pk_bf16(lo.x, lo.y);
            bf[c].u[1] = cvt_pk_bf16(lo.z, lo.w);
            bf[c].u[2] = cvt_pk_bf16(hi.x, hi.y);
            bf[c].u[3] = cvt_pk_bf16(hi.z, hi.w);
        }
    }
    // pin: all B loads consumed above; stage loads issued after -> vmcnt counts
    // ONLY stage loads from here on.
    __builtin_amdgcn_sched_barrier(0);
    STAGE(0);
    STAGE(1);                         // 4 loads outstanding
    __builtin_amdgcn_sched_barrier(0);

    floatx16 acc;
#pragma unroll
    for (int r = 0; r < 16; ++r) acc[r] = 0.f;

    // A-frag addressing: row = mt*32 + (lane&31); 8 quads/row, swizzle row&7.
    const int rl     = lane & 31;
    const int ldsrow = mt * 32 + rl;
    const int sw8    = ldsrow & 7;
    const int q0     = p * 4 + kh * 2;   // first quad of lane's 8 k's in chunk

    // ---- main loop (fully unrolled; bf[c] stays in registers)
#pragma unroll
    for (int c = 0; c < NCH; ++c) {
        if (c + 2 < NCH) {
            STAGE(c + 2);             // outstanding: chunks c,c+1,c+2 partially
            asm volatile("s_waitcnt vmcnt(4)\n\ts_barrier" ::: "memory");
        } else if (c == NCH - 2) {
            asm volatile("s_waitcnt vmcnt(2)\n\ts_barrier" ::: "memory");
        } else {
            asm volatile("s_waitcnt vmcnt(0)\n\ts_barrier" ::: "memory");
        }
        __builtin_amdgcn_sched_barrier(0);   // don't hoist ds_reads above wait

        const float4* rowp = (const float4*)(smem + (c & 3) * BUFW + ldsrow * KC);
        const float4 lo = rowp[q0 ^ sw8];
        const float4 hi = rowp[(q0 + 1) ^ sw8];
        Frag a;
        a.u[0] = cvt_pk_bf16(lo.x, lo.y);
        a.u[1] = cvt_pk_bf16(lo.z, lo.w);
        a.u[2] = cvt_pk_bf16(hi.x, hi.y);
        a.u[3] = cvt_pk_bf16(hi.z, hi.w);
        acc = __builtin_amdgcn_mfma_f32_32x32x16_bf16(a.v, bf[c].v, acc, 0, 0, 0);
    }

    // ---- epilogue: merge parity partials in LDS raw[n][e] (stride 33).
    // C mapping (m74/m101): col=lane&31, row=(r&3)+8*(r>>2)+4*(lane>>5).
    // p==0 writes smem[0..4222] (buf0/1 region); last computes read buf2/3 ->
    // disjoint, race-free before the barrier.
    if (p == 0) {
#pragma unroll
        for (int r = 0; r < 16; ++r) {
            const int rowl = (r & 3) + 8 * (r >> 2) + 4 * kh;
            smem[(mt * 32 + rowl) * 33 + e_b] = acc[r];
        }
    }
    __syncthreads();
    if (p == 1) {
#pragma unroll
        for (int r = 0; r < 16; ++r) {
            const int rowl = (r & 3) + 8 * (r >> 2) + 4 * kh;
            smem[(mt * 32 + rowl) * 33 + e_b] += acc[r];
        }
    }
    __syncthreads();

    // bias + exp(sigma half): 4096 slots, 8 per thread
#pragma unroll
    for (int jj = 0; jj < 8; ++jj) {
        const int item = tid * 8 + jj;
        const int n = item >> 5;
        const int e = item & 31;
        float v = smem[n * 33 + e] + bias[e];
        if (e >= P_) v = fmaxf(expf(v), 1e-6f);
        smem[n * 33 + e] = v;
    }
    __syncthreads();

    // gather: out[b,t,f] = sum_{n: t-8n in [0,16)} raw[n][.] / cnt
    const int TF = T * F_;
    const size_t halfoff = (size_t)B_ * TF;
    for (int item = tid; item < 2 * T; item += 512) {
        const int half = (item >= T) ? 1 : 0;
        const int t    = item - half * T;
        const int nmax = min(NP_ - 1, t >> 3);
        const int nmin = (t > 8) ? ((t - 8) >> 3) : 0;
        float sum = 0.f;
        const int cnt = nmax - nmin + 1;
        for (int nn = nmin; nn <= nmax; ++nn)
            sum += smem[nn * 33 + (half << 4) + (t - (nn << 3))];
        const float r = (cnt > 0) ? sum / (float)cnt : 0.f;
        out[(size_t)half * halfoff + (size_t)b * TF + (size_t)t * F_ + f] = r;
    }
}

extern "C" void kernel_launch(void* const* d_in, const int* in_sizes, int n_in,
                              void* d_out, int out_size, void* d_ws, size_t ws_size,
                              hipStream_t stream)
{
    const float* ts   = (const float*)d_in[0];
    const float* W    = (const float*)d_in[1];
    const float* bias = (const float*)d_in[2];
    float* out = (float*)d_out;

    // T derived on host from out_size = 2 * B * T * F
    const int T = out_size / (2 * B_ * F_);

    dim3 grid(B_ * F_);   // 512 blocks, one per (b, f), XCD-encoded id
    dim3 block(512);
    pd_kernel<<<grid, block, 0, stream>>>(ts, W, bias, out, T);
}

// Round 11
// 42.024 us; speedup vs baseline: 1.0205x; 1.0205x over previous
//
#include <hip/hip_runtime.h>
#include <math.h>

// Problem constants (fixed by the reference)
#define B_   16
#define F_   32
#define NP_  128   // rows per (b,f) panel
#define D_   512
#define P_   16
#define KC   32            // K-chunk in floats (128 B per row per chunk)
#define NCH  (D_ / KC)     // 16 chunks; each = 2 MFMA k-steps (K=16)
#define BUFW (NP_ * KC)    // 4096 floats per buffer (16 KB)

typedef __attribute__((ext_vector_type(8)))  short  short8;   // 8 bf16 = 4 VGPR
typedef __attribute__((ext_vector_type(16))) float  floatx16; // 32x32 acc

union Frag { short8 v; unsigned int u[4]; };

__device__ inline unsigned int cvt_pk_bf16(float lo, float hi) {
    unsigned int r;
    asm volatile("v_cvt_pk_bf16_f32 %0, %1, %2" : "=v"(r) : "v"(lo), "v"(hi));
    return r;   // low 16 = bf16(lo), high 16 = bf16(hi)
}

// 512 threads = 8 waves = 4 M-tiles(32 rows) x 2 K-parities; 2 blocks/CU.
// MFMA GEMM (bf16 in / fp32 acc). This round: (1) DMA starts BEFORE the
// B-preload so the uncoalesced W gather latency hides under the first 48 KB
// of staging; (2) depth-3 ring with stage-AFTER-barrier:
//   iter c: vmcnt(4) -> s_barrier -> STAGE(c+3) -> compute(c)
// overwrite target buf[(c+3)&3]=buf[(c-1)&3]; its last reader compute(c-1)
// finished before this barrier -> race-free; chunk c has ~3 iters of slack.
__global__ __launch_bounds__(512, 4)
void pd_kernel(const float* __restrict__ ts,
               const float* __restrict__ W,
               const float* __restrict__ bias,
               float* __restrict__ out, int T)
{
    __shared__ float smem[4 * BUFW];   // 64 KB ring; reused by epilogue

    const int tid  = threadIdx.x;
    const int lane = tid & 63;
    const int wave = tid >> 6;       // 0..7
    const int mt   = wave & 3;       // M-tile: rows 32*mt .. +31
    const int p    = wave >> 2;      // k-step parity (0/1)

    // XCD-aware block-id encoding (proven: WRITE_SIZE at ideal ~4.1 MB)
    const int d = blockIdx.x;
    const int b = (d & 7) | ((d >> 8) << 3);
    const int f = (d >> 3) & 31;
    const float* __restrict__ tsb = ts + ((size_t)b * F_ + f) * NP_ * D_;

    // Stage chunk cc into ring buffer cc&3. LDS slot (row rr, quad ql) holds
    // global quad ql^(rr&7) — bijective per row; read side uses same XOR.
    auto STAGE = [&](int cc) {
        const int k0 = cc * KC;
        float* dstb = smem + (cc & 3) * BUFW;
#pragma unroll
        for (int it = 0; it < 2; ++it) {
            int slot = it * 512 + tid;       // 0..1023 16B-slots (128 rows x 8 quads)
            int rr = slot >> 3;
            int ql = slot & 7;
            int qg = ql ^ (rr & 7);
            const float* src = tsb + rr * D_ + k0 + (qg << 2);
            __builtin_amdgcn_global_load_lds(
                (const __attribute__((address_space(1))) unsigned int*)src,
                (__attribute__((address_space(3))) unsigned int*)&dstb[slot << 2],
                16, 0, 0);
        }
    };

    // ---- start the DMA stream FIRST (prologue depth 3 = 48 KB in flight)
    STAGE(0);
    STAGE(1);
    STAGE(2);
    __builtin_amdgcn_sched_barrier(0);

    // ---- B preload (overlaps the DMA above): wave's 16 k-steps s = 2c+p.
    // Lane: e=lane&31, k-half kh=lane>>5. L2-resident gather; its consume
    // drain coincides with waiting for chunk 0 anyway.
    const int e_b = lane & 31;
    const int kh  = lane >> 5;
    Frag bf[NCH];
    {
        const float* wb = W + (size_t)e_b * D_ + kh * 8;
#pragma unroll
        for (int c = 0; c < NCH; ++c) {
            const int k = c * 32 + p * 16;
            const float4 lo = *(const float4*)(wb + k);
            const float4 hi = *(const float4*)(wb + k + 4);
            bf[c].u[0] = cvt_pk_bf16(lo.x, lo.y);
            bf[c].u[1] = cvt_pk_bf16(lo.z, lo.w);
            bf[c].u[2] = cvt_pk_bf16(hi.x, hi.y);
            bf[c].u[3] = cvt_pk_bf16(hi.z, hi.w);
        }
    }
    __builtin_amdgcn_sched_barrier(0);

    floatx16 acc;
#pragma unroll
    for (int r = 0; r < 16; ++r) acc[r] = 0.f;

    // A-frag addressing: row = mt*32 + (lane&31); 8 quads/row, swizzle row&7.
    const int rl     = lane & 31;
    const int ldsrow = mt * 32 + rl;
    const int sw8    = ldsrow & 7;
    const int q0     = p * 4 + kh * 2;   // first quad of lane's 8 k's in chunk

    // ---- main loop (fully unrolled; bf[c] stays in registers).
    // Entering iter c: outstanding stage loads = chunks c..min(c+2,15).
#pragma unroll
    for (int c = 0; c < NCH; ++c) {
        if (c <= NCH - 4) {
            asm volatile("s_waitcnt vmcnt(4)\n\ts_barrier" ::: "memory");
        } else if (c == NCH - 3) {
            asm volatile("s_waitcnt vmcnt(4)\n\ts_barrier" ::: "memory");
        } else if (c == NCH - 2) {
            asm volatile("s_waitcnt vmcnt(2)\n\ts_barrier" ::: "memory");
        } else {
            asm volatile("s_waitcnt vmcnt(0)\n\ts_barrier" ::: "memory");
        }
        if (c + 3 < NCH) STAGE(c + 3);       // overwrites buf[(c-1)&3]: safe,
                                             // compute(c-1) done pre-barrier
        __builtin_amdgcn_sched_barrier(0);   // pin ds_reads below wait+stage

        const float4* rowp = (const float4*)(smem + (c & 3) * BUFW + ldsrow * KC);
        const float4 lo = rowp[q0 ^ sw8];
        const float4 hi = rowp[(q0 + 1) ^ sw8];
        Frag a;
        a.u[0] = cvt_pk_bf16(lo.x, lo.y);
        a.u[1] = cvt_pk_bf16(lo.z, lo.w);
        a.u[2] = cvt_pk_bf16(hi.x, hi.y);
        a.u[3] = cvt_pk_bf16(hi.z, hi.w);
        acc = __builtin_amdgcn_mfma_f32_32x32x16_bf16(a.v, bf[c].v, acc, 0, 0, 0);
    }

    // ---- epilogue: merge parity partials in LDS raw[n][e] (stride 33).
    // C mapping (m74/m101): col=lane&31, row=(r&3)+8*(r>>2)+4*(lane>>5).
    // p==0 writes smem[0..4222] (buf0/buf1 region); last computes read buf3
    // -> disjoint, race-free before the barrier.
    if (p == 0) {
#pragma unroll
        for (int r = 0; r < 16; ++r) {
            const int rowl = (r & 3) + 8 * (r >> 2) + 4 * kh;
            smem[(mt * 32 + rowl) * 33 + e_b] = acc[r];
        }
    }
    __syncthreads();
    if (p == 1) {
#pragma unroll
        for (int r = 0; r < 16; ++r) {
            const int rowl = (r & 3) + 8 * (r >> 2) + 4 * kh;
            smem[(mt * 32 + rowl) * 33 + e_b] += acc[r];
        }
    }
    __syncthreads();

    // bias + exp(sigma half): 4096 slots, 8 per thread
#pragma unroll
    for (int jj = 0; jj < 8; ++jj) {
        const int item = tid * 8 + jj;
        const int n = item >> 5;
        const int e = item & 31;
        float v = smem[n * 33 + e] + bias[e];
        if (e >= P_) v = fmaxf(expf(v), 1e-6f);
        smem[n * 33 + e] = v;
    }
    __syncthreads();

    // gather: out[b,t,f] = sum_{n: t-8n in [0,16)} raw[n][.] / cnt
    const int TF = T * F_;
    const size_t halfoff = (size_t)B_ * TF;
    for (int item = tid; item < 2 * T; item += 512) {
        const int half = (item >= T) ? 1 : 0;
        const int t    = item - half * T;
        const int nmax = min(NP_ - 1, t >> 3);
        const int nmin = (t > 8) ? ((t - 8) >> 3) : 0;
        float sum = 0.f;
        const int cnt = nmax - nmin + 1;
        for (int nn = nmin; nn <= nmax; ++nn)
            sum += smem[nn * 33 + (half << 4) + (t - (nn << 3))];
        const float r = (cnt > 0) ? sum / (float)cnt : 0.f;
        out[(size_t)half * halfoff + (size_t)b * TF + (size_t)t * F_ + f] = r;
    }
}

extern "C" void kernel_launch(void* const* d_in, const int* in_sizes, int n_in,
                              void* d_out, int out_size, void* d_ws, size_t ws_size,
                              hipStream_t stream)
{
    const float* ts   = (const float*)d_in[0];
    const float* W    = (const float*)d_in[1];
    const float* bias = (const float*)d_in[2];
    float* out = (float*)d_out;

    // T derived on host from out_size = 2 * B * T * F
    const int T = out_size / (2 * B_ * F_);

    dim3 grid(B_ * F_);   // 512 blocks, one per (b, f), XCD-encoded id
    dim3 block(512);
    pd_kernel<<<grid, block, 0, stream>>>(ts, W, bias, out, T);
}